// Round 7
// baseline (518.042 us; speedup 1.0000x reference)
//
#include <hip/hip_runtime.h>

#define NNODES 100000
#define NREL 8
#define EMB 64
#define RN (NREL * NNODES)           // 800000 CSR segments (keys n*8+r)
#define NB_SCAN ((RN + 1023) / 1024) // 782 scan blocks
#define NB 32                        // nodes per fused block
#define FBLOCKS (NNODES / NB)        // 3125, exact

typedef __attribute__((ext_vector_type(8))) short bf16x8;   // 8 bf16 (4 VGPRs)
typedef __attribute__((ext_vector_type(4))) float f32x4;

__device__ inline unsigned short f2bf(float f) {
    union { float f; unsigned u; } v; v.f = f;
    return (unsigned short)((v.u + 0x7FFFu + ((v.u >> 16) & 1u)) >> 16);  // RNE
}

// ---------------------------------------------------------------------------
// K1: degree count per node-major key (n*8 + r)
// ---------------------------------------------------------------------------
__global__ void k_degree(const int* __restrict__ rows, int* __restrict__ deg, int E) {
    int e = blockIdx.x * blockDim.x + threadIdx.x;
    if (e < E) {
        int row = rows[e];
        int r = row / NNODES;            // magic-mul
        int n = row - r * NNODES;
        atomicAdd(&deg[n * NREL + r], 1);
    }
}

// ---------------------------------------------------------------------------
// Scan step 1: per-1024-chunk sums
// ---------------------------------------------------------------------------
__global__ void k_bsum(const int* __restrict__ deg, int* __restrict__ bsum) {
    int t = threadIdx.x;
    int base = blockIdx.x * 1024 + t * 4;
    int s = 0;
    if (base < RN) { int4 v = *reinterpret_cast<const int4*>(deg + base); s = v.x + v.y + v.z + v.w; }
#pragma unroll
    for (int d = 1; d < 64; d <<= 1) s += __shfl_xor(s, d);
    __shared__ int ws[4];
    if ((t & 63) == 0) ws[t >> 6] = s;
    __syncthreads();
    if (t == 0) bsum[blockIdx.x] = ws[0] + ws[1] + ws[2] + ws[3];
}

// ---------------------------------------------------------------------------
// Scan step 2: exclusive scan of the 782 chunk sums (single block)
// ---------------------------------------------------------------------------
__global__ void k_scan_mid(const int* __restrict__ bsum, int* __restrict__ boff) {
    __shared__ int tmp[1024];
    int t = threadIdx.x;
    int v0 = (t < NB_SCAN) ? bsum[t] : 0;
    tmp[t] = v0;
    __syncthreads();
    for (int d = 1; d < 1024; d <<= 1) {
        int u = (t >= d) ? tmp[t - d] : 0;
        __syncthreads();
        tmp[t] += u;
        __syncthreads();
    }
    if (t < NB_SCAN) boff[t] = tmp[t] - v0;   // exclusive
}

// ---------------------------------------------------------------------------
// Scan step 3: full exclusive row_ptr (start offsets)
// ---------------------------------------------------------------------------
__global__ void k_rowptr(const int* __restrict__ deg, const int* __restrict__ boff,
                         int* __restrict__ row_ptr) {
    int t = threadIdx.x;
    int base = blockIdx.x * 1024 + t * 4;
    int4 v = {0, 0, 0, 0};
    if (base < RN) v = *reinterpret_cast<const int4*>(deg + base);
    int s = v.x + v.y + v.z + v.w;
    int lane = t & 63;
    int inc = s;
#pragma unroll
    for (int d = 1; d < 64; d <<= 1) { int u = __shfl_up(inc, d); if (lane >= d) inc += u; }
    __shared__ int ws[4];
    if (lane == 63) ws[t >> 6] = inc;
    __syncthreads();
    int off = boff[blockIdx.x];
    int wid = t >> 6;
    for (int i = 0; i < wid; ++i) off += ws[i];
    int run = off + inc - s;                  // exclusive prefix for this thread
    if (base < RN) {
        int4 o;
        o.x = run; run += v.x;
        o.y = run; run += v.y;
        o.z = run; run += v.z;
        o.w = run;
        *reinterpret_cast<int4*>(row_ptr + base) = o;
    }
}

// ---------------------------------------------------------------------------
// Counting-sort scatter of per-edge payload:
//   .x = c | r<<17 | (n&31)<<20   (c<2^17, r<8, block-local node id 5 bits)
//   .y = inv_deg bits
// Mutates row_ptr: afterwards row_ptr[key] == segment END.
// ---------------------------------------------------------------------------
__global__ void k_sort(const int* __restrict__ rows, const int* __restrict__ cols,
                       const int* __restrict__ deg, int* __restrict__ rptr,
                       int2* __restrict__ pairs, int E) {
    int e = blockIdx.x * blockDim.x + threadIdx.x;
    if (e >= E) return;
    int row = rows[e];
    int r = row / NNODES;
    int n = row - r * NNODES;
    int key = n * NREL + r;
    int p = atomicAdd(&rptr[key], 1);
    float inv = __builtin_amdgcn_rcpf((float)deg[key]);   // deg>=1 for this key
    pairs[p] = make_int2(cols[e] | (r << 17) | ((n & (NB - 1)) << 20),
                         __float_as_int(inv));
}

// ---------------------------------------------------------------------------
// W prep: build the swizzled bf16 LDS image of W once in global memory.
// Element (f, kglob=r*64+k):  byte = (f<<10 | kglob<<1) ^ ((f&7)<<4)
// ---------------------------------------------------------------------------
__global__ void k_wprep(const float* __restrict__ W, unsigned short* __restrict__ Wbf) {
    int t = blockIdx.x * blockDim.x + threadIdx.x;   // 0..32767, flat [r][k][f]
    if (t >= NREL * EMB * EMB) return;
    int f  = t & 63;
    int kg = t >> 6;                                 // r*64 + k
    int byte = ((f << 10) + (kg << 1)) ^ ((f & 7) << 4);
    Wbf[byte >> 1] = f2bf(W[t]);
}

// ---------------------------------------------------------------------------
// Fused SpMM + GEMM: block = 512 thr (8 waves) owns NB=32 nodes.
// Phase 1: zero h LDS (f32 [32][512], XOR-swizzled) + flat-copy Wbf -> LDS.
// Phase 2: edge-parallel aggregation, ds_add_f32 (h[nloc][r*64+lane] += inv*x).
// Phase 3: MFMA 16x16x32: wave w -> C-tile (nt=w>>2, ft=w&3); A=h (cvt bf16),
//          B=W from LDS; out = relu(D) written f32 directly.
// ---------------------------------------------------------------------------
__global__ __launch_bounds__(512) void k_fused(const int* __restrict__ rptr,
                                               const int2* __restrict__ pairs,
                                               const float* __restrict__ x,
                                               const unsigned short* __restrict__ Wbf,
                                               float* __restrict__ out) {
    __shared__ int4 smem[8192];                      // 128 KiB: h (64K) | Ws (64K)
    char* hs = (char*)smem;                          // f32 [32][512] swizzled
    char* Ws = (char*)smem + 65536;                  // bf16 [64][512] swizzled

    const int tid  = threadIdx.x;
    const int lane = tid & 63;
    const int wid  = tid >> 6;
    const int nb0  = blockIdx.x * NB;

    // ---- Phase 1: zero h + copy W image (linear 16B ops) ----
#pragma unroll
    for (int i = 0; i < 8; ++i) {
        int idx = tid + i * 512;                     // 0..4095 chunks of 16B
        reinterpret_cast<f32x4*>(hs)[idx] = f32x4{};
        reinterpret_cast<bf16x8*>(Ws)[idx] = reinterpret_cast<const bf16x8*>(Wbf)[idx];
    }
    __syncthreads();

    // ---- Phase 2: edge-parallel aggregation ----
    const int s_blk = (nb0 == 0) ? 0 : rptr[nb0 * NREL - 1];
    const int e_blk = rptr[(nb0 + NB) * NREL - 1];
    const int lane4 = lane << 2;

    for (int base = s_blk + wid * 64; base < e_blk; base += 8 * 64) {
        int m = e_blk - base; if (m > 64) m = 64;
        int2 pv = (lane < m) ? pairs[base + lane] : make_int2(0, 0);
        for (int j0 = 0; j0 < m; j0 += 8) {
#pragma unroll
            for (int u = 0; u < 8; ++u) {
                int j  = j0 + u;
                int jc = j < m ? j : 0;                          // uniform clamp
                int px = __builtin_amdgcn_readlane(pv.x, jc);
                int ib = __builtin_amdgcn_readlane(pv.y, jc);
                float inv = (j < m) ? __int_as_float(ib) : 0.f;  // dead edge -> +0
                int c    = px & 0x1FFFF;
                int r    = (px >> 17) & 7;
                int nloc = px >> 20;
                float v = x[(size_t)c * EMB + lane] * inv;
                int lb = ((nloc << 11) + (r << 8) + lane4) ^ ((nloc & 7) << 4);
                atomicAdd(reinterpret_cast<float*>(hs + lb), v);
            }
        }
    }
    __syncthreads();

    // ---- Phase 3: MFMA ----
    const int nt = wid >> 2;             // node tile 0..1
    const int ft = wid & 3;              // f tile 0..3
    const int arow = lane & 15;
    const int kgrp = lane >> 4;
    const int row  = nt * 16 + arow;     // A row (node local)
    const int amask = (row & 7) << 4;
    const int col  = ft * 16 + arow;     // B col (f)
    const int bmask = (col & 7) << 4;

    f32x4 acc = {};
#pragma unroll 4
    for (int k0 = 0; k0 < 512; k0 += 32) {
        int abyte = ((row << 11) + ((k0 + kgrp * 8) << 2)) ^ amask;
        f32x4 a0 = *reinterpret_cast<const f32x4*>(hs + abyte);
        f32x4 a1 = *reinterpret_cast<const f32x4*>(hs + (abyte ^ 16));
        bf16x8 A;
#pragma unroll
        for (int j = 0; j < 4; ++j) {
            A[j]     = (short)f2bf(a0[j]);
            A[j + 4] = (short)f2bf(a1[j]);
        }
        int bbyte = ((col << 10) + ((k0 + kgrp * 8) << 1)) ^ bmask;
        bf16x8 B = *reinterpret_cast<const bf16x8*>(Ws + bbyte);
        acc = __builtin_amdgcn_mfma_f32_16x16x32_bf16(A, B, acc, 0, 0, 0);
    }

    // D: col = arow (f within tile), rows = kgrp*4 + i (node within tile)
    const int nglob = nb0 + nt * 16 + kgrp * 4;
#pragma unroll
    for (int i = 0; i < 4; ++i)
        out[(size_t)(nglob + i) * EMB + ft * 16 + arow] = fmaxf(acc[i], 0.f);
}

// ---------------------------------------------------------------------------
extern "C" void kernel_launch(void* const* d_in, const int* in_sizes, int n_in,
                              void* d_out, int out_size, void* d_ws, size_t ws_size,
                              hipStream_t stream) {
    const float* x    = (const float*)d_in[0];
    const float* w    = (const float*)d_in[1];
    const int*   rows = (const int*)d_in[2];   // JAX x64-disabled -> int32
    const int*   cols = (const int*)d_in[3];
    float*       out  = (float*)d_out;
    int E = in_sizes[2];

    char* ws = (char*)d_ws;
    int*            deg   = (int*)(ws);                        // 3.2 MB
    int*            rptr  = (int*)(ws + 3200000);              // 3.2 MB
    int*            bsum  = (int*)(ws + 6400000);              // 4 KB
    int*            boff  = (int*)(ws + 6404096);              // 4 KB
    int2*           pairs = (int2*)(ws + 6408192);             // 8 MB
    unsigned short* Wbf   = (unsigned short*)(ws + 14408192);  // 64 KB

    hipMemsetAsync(deg, 0, (size_t)RN * sizeof(int), stream);

    k_degree<<<(E + 255) / 256, 256, 0, stream>>>(rows, deg, E);
    k_bsum<<<NB_SCAN, 256, 0, stream>>>(deg, bsum);
    k_scan_mid<<<1, 1024, 0, stream>>>(bsum, boff);
    k_rowptr<<<NB_SCAN, 256, 0, stream>>>(deg, boff, rptr);
    k_sort<<<(E + 255) / 256, 256, 0, stream>>>(rows, cols, deg, rptr, pairs, E);
    k_wprep<<<(NREL * EMB * EMB + 255) / 256, 256, 0, stream>>>(w, Wbf);
    k_fused<<<FBLOCKS, 512, 0, stream>>>(rptr, pairs, x, Wbf, out);
}

// Round 8
// 182.782 us; speedup vs baseline: 2.8342x; 2.8342x over previous
//
#include <hip/hip_runtime.h>

#define NNODES 100000
#define NREL 8
#define EMB 64
#define RN (NREL * NNODES)           // 800000 CSR segments (keys n*8+r)
#define YDIM (NREL * EMB)            // 512
#define NB_SCAN ((RN + 1023) / 1024) // 782 scan blocks
#define NSTRIPS (NNODES / 16)        // 6250, exact
#define G1_BLOCKS 1250               // 5 strips per block, exact

typedef __attribute__((ext_vector_type(8))) short bf16x8;   // 8 bf16 (4 VGPRs)
typedef __attribute__((ext_vector_type(4))) float f32x4;

__device__ inline unsigned short f2bf(float f) {
    union { float f; unsigned u; } v; v.f = f;
    return (unsigned short)((v.u + 0x7FFFu + ((v.u >> 16) & 1u)) >> 16);  // RNE
}
__device__ inline float bf2f(unsigned short u) {
    union { unsigned u; float f; } v; v.u = ((unsigned)u) << 16; return v.f;
}

// ---------------------------------------------------------------------------
// K1: degree count per node-major key (n*8 + r)
// ---------------------------------------------------------------------------
__global__ void k_degree(const int* __restrict__ rows, int* __restrict__ deg, int E) {
    int e = blockIdx.x * blockDim.x + threadIdx.x;
    if (e < E) {
        int row = rows[e];
        int r = row / NNODES;            // magic-mul
        int n = row - r * NNODES;
        atomicAdd(&deg[n * NREL + r], 1);
    }
}

// ---------------------------------------------------------------------------
// Scan step 1: per-1024-chunk sums
// ---------------------------------------------------------------------------
__global__ void k_bsum(const int* __restrict__ deg, int* __restrict__ bsum) {
    int t = threadIdx.x;
    int base = blockIdx.x * 1024 + t * 4;
    int s = 0;
    if (base < RN) { int4 v = *reinterpret_cast<const int4*>(deg + base); s = v.x + v.y + v.z + v.w; }
#pragma unroll
    for (int d = 1; d < 64; d <<= 1) s += __shfl_xor(s, d);
    __shared__ int ws[4];
    if ((t & 63) == 0) ws[t >> 6] = s;
    __syncthreads();
    if (t == 0) bsum[blockIdx.x] = ws[0] + ws[1] + ws[2] + ws[3];
}

// ---------------------------------------------------------------------------
// Scan step 2: exclusive scan of the 782 chunk sums (single block)
// ---------------------------------------------------------------------------
__global__ void k_scan_mid(const int* __restrict__ bsum, int* __restrict__ boff) {
    __shared__ int tmp[1024];
    int t = threadIdx.x;
    int v0 = (t < NB_SCAN) ? bsum[t] : 0;
    tmp[t] = v0;
    __syncthreads();
    for (int d = 1; d < 1024; d <<= 1) {
        int u = (t >= d) ? tmp[t - d] : 0;
        __syncthreads();
        tmp[t] += u;
        __syncthreads();
    }
    if (t < NB_SCAN) boff[t] = tmp[t] - v0;   // exclusive
}

// ---------------------------------------------------------------------------
// Scan step 3: full exclusive row_ptr (start offsets)
// ---------------------------------------------------------------------------
__global__ void k_rowptr(const int* __restrict__ deg, const int* __restrict__ boff,
                         int* __restrict__ row_ptr) {
    int t = threadIdx.x;
    int base = blockIdx.x * 1024 + t * 4;
    int4 v = {0, 0, 0, 0};
    if (base < RN) v = *reinterpret_cast<const int4*>(deg + base);
    int s = v.x + v.y + v.z + v.w;
    int lane = t & 63;
    int inc = s;
#pragma unroll
    for (int d = 1; d < 64; d <<= 1) { int u = __shfl_up(inc, d); if (lane >= d) inc += u; }
    __shared__ int ws[4];
    if (lane == 63) ws[t >> 6] = inc;
    __syncthreads();
    int off = boff[blockIdx.x];
    int wid = t >> 6;
    for (int i = 0; i < wid; ++i) off += ws[i];
    int run = off + inc - s;                  // exclusive prefix for this thread
    if (base < RN) {
        int4 o;
        o.x = run; run += v.x;
        o.y = run; run += v.y;
        o.z = run; run += v.z;
        o.w = run;
        *reinterpret_cast<int4*>(row_ptr + base) = o;
    }
}

// ---------------------------------------------------------------------------
// Counting-sort scatter of per-edge payload {packed_src = c*8+r, inv_deg}.
// Mutates row_ptr: afterwards row_ptr[key] == segment END.
// ---------------------------------------------------------------------------
__global__ void k_sort(const int* __restrict__ rows, const int* __restrict__ cols,
                       const int* __restrict__ deg, int* __restrict__ rptr,
                       int2* __restrict__ pairs, int E) {
    int e = blockIdx.x * blockDim.x + threadIdx.x;
    if (e >= E) return;
    int row = rows[e];
    int r = row / NNODES;
    int n = row - r * NNODES;
    int key = n * NREL + r;
    int p = atomicAdd(&rptr[key], 1);
    float inv = __builtin_amdgcn_rcpf((float)deg[key]);   // deg>=1 for this key
    pairs[p] = make_int2(cols[e] * NREL + r, __float_as_int(inv));
}

// ---------------------------------------------------------------------------
// GEMM1: y[c, r*64+f] = sum_k x[c,k] * W[r,k,f]   (bf16 MFMA 16x16x32, K=64)
// Swapped-operand form: D[f][c] tiles. A = W^T fragments (strip-invariant, 32
// VGPRs); B = x row slices loaded directly from global (16B/lane contiguous).
// Epilogue: D written bf16 to a 16KB LDS tile ([16 c][512 f], 16B-unit XOR
// swizzle), then streamed to y as fully-coalesced 16B/lane stores.
// Block = 512 thr (8 waves); wave = one relation, 16 nodes/strip; 5 strips.
// ---------------------------------------------------------------------------
__global__ __launch_bounds__(512) void k_gemm1(const float* __restrict__ x,
                                               const float* __restrict__ W,
                                               unsigned short* __restrict__ y) {
    __shared__ char tile[16384];           // bf16 [16][512], swizzled
    const int tid  = threadIdx.x;
    const int lane = tid & 63;
    const int rel  = tid >> 6;             // wave id = relation
    const int fl   = lane & 15;            // A row (f_local) == B col (c_local)
    const int kgrp = lane >> 4;            // k-group 0..3

    // A fragments: wfrag[ft][ks][j] = W[rel][ks*32 + kgrp*8 + j][ft*16 + fl]
    bf16x8 wfrag[4][2];
#pragma unroll
    for (int ft = 0; ft < 4; ++ft)
#pragma unroll
        for (int ks = 0; ks < 2; ++ks) {
            const float* wp = W + ((size_t)rel * EMB + ks * 32 + kgrp * 8) * EMB
                              + ft * 16 + fl;
            bf16x8 a;
#pragma unroll
            for (int j = 0; j < 8; ++j) a[j] = (short)f2bf(wp[(size_t)j * EMB]);
            wfrag[ft][ks] = a;
        }

    const int wbase = (fl << 10) + (rel << 7) + (kgrp << 3);
    const int wswz  = (fl & 7) << 4;

    for (int strip = blockIdx.x; strip < NSTRIPS; strip += G1_BLOCKS) {
        const int c = strip * 16 + fl;
        const float* xp = x + (size_t)c * EMB + kgrp * 8;
        f32x4 x0 = *reinterpret_cast<const f32x4*>(xp);        // ks=0
        f32x4 x1 = *reinterpret_cast<const f32x4*>(xp + 4);
        f32x4 x2 = *reinterpret_cast<const f32x4*>(xp + 32);   // ks=1
        f32x4 x3 = *reinterpret_cast<const f32x4*>(xp + 36);
        bf16x8 B0, B1;
#pragma unroll
        for (int j = 0; j < 4; ++j) {
            B0[j] = (short)f2bf(x0[j]);  B0[j + 4] = (short)f2bf(x1[j]);
            B1[j] = (short)f2bf(x2[j]);  B1[j + 4] = (short)f2bf(x3[j]);
        }

        f32x4 acc[4] = {f32x4{}, f32x4{}, f32x4{}, f32x4{}};
#pragma unroll
        for (int ft = 0; ft < 4; ++ft) {
            acc[ft] = __builtin_amdgcn_mfma_f32_16x16x32_bf16(wfrag[ft][0], B0, acc[ft], 0, 0, 0);
            acc[ft] = __builtin_amdgcn_mfma_f32_16x16x32_bf16(wfrag[ft][1], B1, acc[ft], 0, 0, 0);
        }

        // D[f][c] -> LDS bf16 tile at [c_local=fl][f_global=rel*64+ft*16+kgrp*4+i]
#pragma unroll
        for (int ft = 0; ft < 4; ++ft) {
            ushort4 o;
            o.x = f2bf(acc[ft][0]); o.y = f2bf(acc[ft][1]);
            o.z = f2bf(acc[ft][2]); o.w = f2bf(acc[ft][3]);
            *reinterpret_cast<ushort4*>(tile + ((wbase + (ft << 5)) ^ wswz)) = o;
        }
        __syncthreads();

        // stream tile -> y, fully coalesced 16B/lane
#pragma unroll
        for (int h = 0; h < 2; ++h) {
            int u  = tid + h * 512;            // 16B unit 0..1023
            int cl = u >> 6;                   // c_local
            bf16x8 v = *reinterpret_cast<const bf16x8*>(tile + ((u << 4) ^ ((cl & 7) << 4)));
            *reinterpret_cast<bf16x8*>(y + (size_t)(strip * 16 + cl) * YDIM + ((u & 63) << 3)) = v;
        }
        __syncthreads();
    }
}

// ---------------------------------------------------------------------------
// Gather: one wave per node; lane = output dim f. Per edge: uniform scalar
// {packed, inv} via readlane -> scalar-base ushort load of y[packed*64+f],
// acc = fmaf(inv, v, acc). 8 independent loads in flight per chunk.
// Writes final out = relu(acc) directly.
// ---------------------------------------------------------------------------
__global__ void k_gather(const int* __restrict__ rptr, const int2* __restrict__ pairs,
                         const unsigned short* __restrict__ yb, float* __restrict__ out) {
    int n = blockIdx.x * (blockDim.x >> 6) + (threadIdx.x >> 6);
    if (n >= NNODES) return;
    const int lane = threadIdx.x & 63;

    int s = (n == 0) ? 0 : rptr[n * NREL - 1];     // wave-uniform broadcast loads
    int e = rptr[n * NREL + NREL - 1];

    float acc = 0.f;
    for (int c0 = s; c0 < e; c0 += 64) {
        int m = e - c0; if (m > 64) m = 64;
        int2 pv = (lane < m) ? pairs[c0 + lane] : make_int2(0, 0);
        for (int j0 = 0; j0 < m; j0 += 8) {
#pragma unroll
            for (int u = 0; u < 8; ++u) {
                int j  = j0 + u;
                int jc = j < m ? j : 0;                         // uniform clamp
                int sp = __builtin_amdgcn_readlane(pv.x, jc);   // scalar packed
                int sb = __builtin_amdgcn_readlane(pv.y, jc);   // scalar inv bits
                float si = (j < m) ? __int_as_float(sb) : 0.f;  // dead edge -> *0
                float v  = bf2f(yb[(size_t)sp * EMB + lane]);
                acc = fmaf(si, v, acc);
            }
        }
    }
    out[(size_t)n * EMB + lane] = fmaxf(acc, 0.f);
}

// ---------------------------------------------------------------------------
extern "C" void kernel_launch(void* const* d_in, const int* in_sizes, int n_in,
                              void* d_out, int out_size, void* d_ws, size_t ws_size,
                              hipStream_t stream) {
    const float* x    = (const float*)d_in[0];
    const float* w    = (const float*)d_in[1];
    const int*   rows = (const int*)d_in[2];   // JAX x64-disabled -> int32
    const int*   cols = (const int*)d_in[3];
    float*       out  = (float*)d_out;
    int E = in_sizes[2];

    char* ws = (char*)d_ws;
    int*            deg   = (int*)(ws);                       // 3.2 MB
    int*            rptr  = (int*)(ws + 3200000);             // 3.2 MB
    int*            bsum  = (int*)(ws + 6400000);             // 4 KB
    int*            boff  = (int*)(ws + 6404096);             // 4 KB
    int2*           pairs = (int2*)(ws + 6408192);            // 8 MB
    unsigned short* y     = (unsigned short*)(ws + 14408192); // 102.4 MB

    hipMemsetAsync(deg, 0, (size_t)RN * sizeof(int), stream);

    k_degree<<<(E + 255) / 256, 256, 0, stream>>>(rows, deg, E);
    k_bsum<<<NB_SCAN, 256, 0, stream>>>(deg, bsum);
    k_scan_mid<<<1, 1024, 0, stream>>>(bsum, boff);
    k_rowptr<<<NB_SCAN, 256, 0, stream>>>(deg, boff, rptr);
    k_sort<<<(E + 255) / 256, 256, 0, stream>>>(rows, cols, deg, rptr, pairs, E);
    k_gemm1<<<G1_BLOCKS, 512, 0, stream>>>(x, w, y);
    k_gather<<<(NNODES + 3) / 4, 256, 0, stream>>>(rptr, pairs, y, out);
}